// Round 4
// baseline (455.966 us; speedup 1.0000x reference)
//
#include <hip/hip_runtime.h>

typedef __bf16 bf16x8 __attribute__((ext_vector_type(8)));
typedef float f32x4 __attribute__((ext_vector_type(4)));

#define NEG_SLOPE 0.01f
#define BN_EPS 1e-5f

static __device__ __forceinline__ unsigned short f2bf(float f) {
    unsigned u = __builtin_bit_cast(unsigned, f);
    unsigned r = (u + 0x7fffu + ((u >> 16) & 1u)) >> 16;
    return (unsigned short)r;
}
static __device__ __forceinline__ float lrelu(float v) {
    return fmaxf(v, 0.f) + NEG_SLOPE * fminf(v, 0.f);
}
static __device__ __forceinline__ f32x4 bn4(f32x4 v, f32x4 sc, f32x4 sh) {
    f32x4 r = v * sc + sh;
    r.x = lrelu(r.x); r.y = lrelu(r.y); r.z = lrelu(r.z); r.w = lrelu(r.w);
    return r;
}

// ---- convert ef, W_edge0, W_edge1 to bf16; block 0 zeros stats[256] ----
__global__ __launch_bounds__(256) void cvt3(const float* __restrict__ a, int na4,
                                            const float* __restrict__ b, int nb4,
                                            const float* __restrict__ c, int nc4,
                                            unsigned short* __restrict__ oa,
                                            unsigned short* __restrict__ ob,
                                            unsigned short* __restrict__ oc,
                                            float* __restrict__ stats) {
    int idx = blockIdx.x * 256 + threadIdx.x;
    if (blockIdx.x == 0) stats[threadIdx.x] = 0.f;   // zeros stats[0..255]
    const float* in; unsigned short* outp; int i;
    if (idx < na4)            { in = a; outp = oa; i = idx; }
    else if (idx < na4 + nb4) { in = b; outp = ob; i = idx - na4; }
    else                      { in = c; outp = oc; i = idx - na4 - nb4; }
    const f32x4 v = *reinterpret_cast<const f32x4*>(in + (size_t)i * 4);
    ushort4 u;
    u.x = f2bf(v.x); u.y = f2bf(v.y); u.z = f2bf(v.z); u.w = f2bf(v.w);
    *reinterpret_cast<ushort4*>(outp + (size_t)i * 4) = u;
}

// ---- root + node-bias matmuls; optional BN(x) on load ----
// y=0: aggr = BN(x)@Wr + br ; y=1: NB = BN(x)@be
__global__ __launch_bounds__(256) void node_mm2(const float* __restrict__ x,
                                                const float* __restrict__ Wr,
                                                const float* __restrict__ br,
                                                float* __restrict__ aggr,
                                                const float* __restrict__ be,
                                                float* __restrict__ NB,
                                                const float* __restrict__ ss) {
    const float* M; const float* bias; float* out;
    if (blockIdx.y == 0) { M = Wr; bias = br; out = aggr; }
    else                 { M = be; bias = nullptr; out = NB; }
    __shared__ float Ml[64][64];
    __shared__ float xl[64][64];
    const int tid = threadIdx.x;
    const int n0 = blockIdx.x * 64;
    for (int f = tid; f < 1024; f += 256) {
        int r = f >> 4, c = f & 15;
        *reinterpret_cast<float4*>(&Ml[r][c * 4]) =
            *reinterpret_cast<const float4*>(M + (size_t)r * 64 + c * 4);
        f32x4 xv = *reinterpret_cast<const f32x4*>(x + (size_t)(n0 + r) * 64 + c * 4);
        if (ss) {
            const f32x4 sc = *reinterpret_cast<const f32x4*>(ss + c * 4);
            const f32x4 sh = *reinterpret_cast<const f32x4*>(ss + 64 + c * 4);
            xv = bn4(xv, sc, sh);
        }
        *reinterpret_cast<f32x4*>(&xl[r][c * 4]) = xv;
    }
    __syncthreads();
    const int o = tid & 63, g = tid >> 6;
    float acc[16] = {};
    for (int i4 = 0; i4 < 16; ++i4) {
        float m0 = Ml[4 * i4 + 0][o], m1 = Ml[4 * i4 + 1][o];
        float m2 = Ml[4 * i4 + 2][o], m3 = Ml[4 * i4 + 3][o];
#pragma unroll
        for (int k = 0; k < 16; ++k) {
            const f32x4 xv = *reinterpret_cast<const f32x4*>(&xl[g + 4 * k][4 * i4]);
            acc[k] += xv.x * m0 + xv.y * m1 + xv.z * m2 + xv.w * m3;
        }
    }
    const float b = bias ? bias[o] : 0.f;
#pragma unroll
    for (int k = 0; k < 16; ++k)
        out[(size_t)(n0 + g + 4 * k) * 64 + o] = acc[k] + b;
}

// ---- fused NNConv message, K-split 4-way: block handles 64 edges x 16 i ----
// D_i[o,e] = sum_d W_i[o,d]*ef[e,d] (MFMA); acc[o,e] += x[src[e],i]*D_i.
// Wave w owns o-slice [16w,16w+16). Chunk 0 also adds NB[src].
__global__ __launch_bounds__(256, 8) void msg_fused(
    const unsigned short* __restrict__ ef_b,   // [E][64] bf16
    const unsigned short* __restrict__ wb,     // [64][64][64] bf16 (i,o,d); + pad
    const float* __restrict__ x,               // [N][64] f32 (pre-BN if ss)
    const float* __restrict__ NB,              // [N][64] f32
    const int* __restrict__ src,
    const int* __restrict__ dst,
    float* __restrict__ aggr,                  // [N][64] f32
    const float* __restrict__ ss) {            // BN scale/shift for x, or null
    __shared__ float xT[16][64];               // xT[ii][e] = BN(x)[src[e]][i0+ii]
    const int tid = threadIdx.x;
    const int e0 = blockIdx.x * 64;
    const int i0 = blockIdx.y * 16;

    {
        const int e = tid & 63, c4 = tid >> 6;     // c4 in 0..3
        const int s = src[e0 + e];
        f32x4 xv = *reinterpret_cast<const f32x4*>(x + (size_t)s * 64 + i0 + 4 * c4);
        if (ss) {
            const f32x4 sc = *reinterpret_cast<const f32x4*>(ss + i0 + 4 * c4);
            const f32x4 sh = *reinterpret_cast<const f32x4*>(ss + 64 + i0 + 4 * c4);
            xv = bn4(xv, sc, sh);
        }
        xT[4 * c4 + 0][e] = xv.x;
        xT[4 * c4 + 1][e] = xv.y;
        xT[4 * c4 + 2][e] = xv.z;
        xT[4 * c4 + 3][e] = xv.w;
    }

    const int w = tid >> 6, l = tid & 63, lg = l >> 4, ln = l & 15;

    // ef B-frags: tile t = edges e0+16t+ln, held in registers
    bf16x8 B0[4], B1[4];
#pragma unroll
    for (int t = 0; t < 4; ++t) {
        const unsigned short* pe = ef_b + (size_t)(e0 + 16 * t + ln) * 64 + 8 * lg;
        B0[t] = *reinterpret_cast<const bf16x8*>(pe);
        B1[t] = *reinterpret_cast<const bf16x8*>(pe + 32);
    }

    // W A-frag: row o=16w+ln of slice i, streamed with register double-buffer
    const unsigned short* pw = wb + (size_t)i0 * 4096 + (size_t)(16 * w + ln) * 64 + 8 * lg;
    bf16x8 Ac0 = *reinterpret_cast<const bf16x8*>(pw);
    bf16x8 Ac1 = *reinterpret_cast<const bf16x8*>(pw + 32);

    __syncthreads();

    f32x4 acc0 = {}, acc1 = {}, acc2 = {}, acc3 = {};
#pragma unroll 2
    for (int ii = 0; ii < 16; ++ii) {
        const unsigned short* pn = pw + (size_t)(ii + 1) * 4096;
        const bf16x8 An0 = *reinterpret_cast<const bf16x8*>(pn);
        const bf16x8 An1 = *reinterpret_cast<const bf16x8*>(pn + 32);
        const float xs0 = xT[ii][ln];
        const float xs1 = xT[ii][16 + ln];
        const float xs2 = xT[ii][32 + ln];
        const float xs3 = xT[ii][48 + ln];
        f32x4 c0 = {}, c1 = {}, c2 = {}, c3 = {};
        c0 = __builtin_amdgcn_mfma_f32_16x16x32_bf16(Ac0, B0[0], c0, 0, 0, 0);
        c1 = __builtin_amdgcn_mfma_f32_16x16x32_bf16(Ac0, B0[1], c1, 0, 0, 0);
        c2 = __builtin_amdgcn_mfma_f32_16x16x32_bf16(Ac0, B0[2], c2, 0, 0, 0);
        c3 = __builtin_amdgcn_mfma_f32_16x16x32_bf16(Ac0, B0[3], c3, 0, 0, 0);
        c0 = __builtin_amdgcn_mfma_f32_16x16x32_bf16(Ac1, B1[0], c0, 0, 0, 0);
        c1 = __builtin_amdgcn_mfma_f32_16x16x32_bf16(Ac1, B1[1], c1, 0, 0, 0);
        c2 = __builtin_amdgcn_mfma_f32_16x16x32_bf16(Ac1, B1[2], c2, 0, 0, 0);
        c3 = __builtin_amdgcn_mfma_f32_16x16x32_bf16(Ac1, B1[3], c3, 0, 0, 0);
        acc0 += xs0 * c0;
        acc1 += xs1 * c1;
        acc2 += xs2 * c2;
        acc3 += xs3 * c3;
        Ac0 = An0; Ac1 = An1;
    }

    // epilogue: chunk 0 adds NB[src]; scatter to aggr[dst]
    f32x4 accs[4] = {acc0, acc1, acc2, acc3};
    const int ob = 16 * w + 4 * lg;
#pragma unroll
    for (int t = 0; t < 4; ++t) {
        const int e = e0 + 16 * t + ln;
        const int d = dst[e];
        f32x4 add = accs[t];
        if (blockIdx.y == 0) {
            const int s = src[e];
            const f32x4 nb = *reinterpret_cast<const f32x4*>(NB + (size_t)s * 64 + ob);
            add += nb;
        }
#pragma unroll
        for (int rr = 0; rr < 4; ++rr)
            atomicAdd(aggr + (size_t)d * 64 + ob + rr, add[rr]);
    }
}

// ---- BN statistics ----
__global__ __launch_bounds__(256) void bn_stats(const float* __restrict__ h,
                                                float* __restrict__ sums) {
    const int tid = threadIdx.x;
    const int o = tid & 63, g = tid >> 6;
    const int n0 = blockIdx.x * 128;
    float s = 0.f, s2 = 0.f;
    for (int k = 0; k < 32; ++k) {
        float v = h[(size_t)(n0 + g * 32 + k) * 64 + o];
        s += v; s2 += v * v;
    }
    __shared__ float red[2][4][64];
    red[0][g][o] = s; red[1][g][o] = s2;
    __syncthreads();
    if (g == 0) {
        s  = red[0][0][o] + red[0][1][o] + red[0][2][o] + red[0][3][o];
        s2 = red[1][0][o] + red[1][1][o] + red[1][2][o] + red[1][3][o];
        atomicAdd(&sums[o], s);
        atomicAdd(&sums[64 + o], s2);
    }
}

__global__ void bn_finalize(const float* __restrict__ sums,
                            const float* __restrict__ gamma,
                            const float* __restrict__ beta,
                            float* __restrict__ ss, float invN) {
    const int o = threadIdx.x;   // 64 threads
    float mean = sums[o] * invN;
    float var = sums[64 + o] * invN - mean * mean;
    float sc = gamma[o] * rsqrtf(var + BN_EPS);
    ss[o] = sc;
    ss[64 + o] = beta[o] - mean * sc;
}

// ---- final: out[n,q] = sum_o BN(x)[n,o]*W_lin[q,o] + b_lin[q] ----
__global__ __launch_bounds__(256) void out_kernel(const float* __restrict__ x2,
                                                  const float* __restrict__ Wl,
                                                  const float* __restrict__ bl,
                                                  float* __restrict__ out,
                                                  const float* __restrict__ ss) {
    __shared__ float Wt[64][129];
    __shared__ float xl[64][64];
    const int tid = threadIdx.x;
    const int n0 = blockIdx.x * 64;
    for (int f = tid; f < 8192; f += 256) {
        int q = f >> 6, o = f & 63;
        Wt[o][q] = Wl[f];
    }
    for (int f = tid; f < 1024; f += 256) {
        int r = f >> 4, c = f & 15;
        f32x4 xv = *reinterpret_cast<const f32x4*>(x2 + (size_t)(n0 + r) * 64 + c * 4);
        const f32x4 sc = *reinterpret_cast<const f32x4*>(ss + c * 4);
        const f32x4 sh = *reinterpret_cast<const f32x4*>(ss + 64 + c * 4);
        xv = bn4(xv, sc, sh);
        *reinterpret_cast<f32x4*>(&xl[r][c * 4]) = xv;
    }
    __syncthreads();
    const int q = tid & 127, ng = tid >> 7;
    float acc[32] = {};
    for (int o4 = 0; o4 < 16; ++o4) {
        float w0 = Wt[4 * o4 + 0][q], w1 = Wt[4 * o4 + 1][q];
        float w2 = Wt[4 * o4 + 2][q], w3 = Wt[4 * o4 + 3][q];
#pragma unroll
        for (int k = 0; k < 32; ++k) {
            const f32x4 xv = *reinterpret_cast<const f32x4*>(&xl[ng + 2 * k][4 * o4]);
            acc[k] += xv.x * w0 + xv.y * w1 + xv.z * w2 + xv.w * w3;
        }
    }
    const float b = bl[q];
#pragma unroll
    for (int k = 0; k < 32; ++k)
        out[(size_t)(n0 + ng + 2 * k) * 128 + q] = acc[k] + b;
}

extern "C" void kernel_launch(void* const* d_in, const int* in_sizes, int n_in,
                              void* d_out, int out_size, void* d_ws, size_t ws_size,
                              hipStream_t stream) {
    const float* nf      = (const float*)d_in[0];
    const int*   ei      = (const int*)d_in[1];
    const float* ef      = (const float*)d_in[2];
    const float* W_edge0 = (const float*)d_in[4];
    const float* b_edge0 = (const float*)d_in[5];
    const float* W_root0 = (const float*)d_in[6];
    const float* b_root0 = (const float*)d_in[7];
    const float* gamma0  = (const float*)d_in[8];
    const float* beta0   = (const float*)d_in[9];
    const float* W_edge1 = (const float*)d_in[10];
    const float* b_edge1 = (const float*)d_in[11];
    const float* W_root1 = (const float*)d_in[12];
    const float* b_root1 = (const float*)d_in[13];
    const float* gamma1  = (const float*)d_in[14];
    const float* beta1   = (const float*)d_in[15];
    const float* W_lin   = (const float*)d_in[16];
    const float* b_lin   = (const float*)d_in[17];

    const int N = in_sizes[0] / 64;   // 8192
    const int E = in_sizes[1] / 2;    // 32768
    const int* src = ei;
    const int* dst = ei + E;

    unsigned short* ef_b = (unsigned short*)d_ws;          // E*64
    unsigned short* wb0  = ef_b + (size_t)E * 64;          // 64*64*64
    unsigned short* wb1  = wb0 + 262144;                   // 64*64*64
    unsigned short* pad  = wb1 + 262144;                   // 4096 (prefetch overrun)
    float* aggr0 = (float*)(pad + 4096);                   // N*64
    float* aggr1 = aggr0 + (size_t)N * 64;                 // N*64
    float* NBbuf = aggr1 + (size_t)N * 64;                 // N*64
    float* stats = NBbuf + (size_t)N * 64;                 // 256
    float* ssbuf = stats + 256;                            // 256

    const float invN = 1.0f / (float)N;
    const int na4 = E * 64 / 4;          // 524288
    const int nw4 = 262144 / 4;          // 65536

    cvt3<<<(na4 + 2 * nw4) / 256, 256, 0, stream>>>(ef, na4, W_edge0, nw4, W_edge1, nw4,
                                                    ef_b, wb0, wb1, stats);

    // ---- layer 0 ----
    node_mm2<<<dim3(N / 64, 2), 256, 0, stream>>>(nf, W_root0, b_root0, aggr0,
                                                  b_edge0, NBbuf, nullptr);
    msg_fused<<<dim3(E / 64, 4), 256, 0, stream>>>(ef_b, wb0, nf, NBbuf, src, dst,
                                                   aggr0, nullptr);
    bn_stats<<<N / 128, 256, 0, stream>>>(aggr0, stats);
    bn_finalize<<<1, 64, 0, stream>>>(stats, gamma0, beta0, ssbuf, invN);

    // ---- layer 1 (x1 = BN(aggr0) applied on load everywhere) ----
    node_mm2<<<dim3(N / 64, 2), 256, 0, stream>>>(aggr0, W_root1, b_root1, aggr1,
                                                  b_edge1, NBbuf, ssbuf);
    msg_fused<<<dim3(E / 64, 4), 256, 0, stream>>>(ef_b, wb1, aggr0, NBbuf, src, dst,
                                                   aggr1, ssbuf);
    bn_stats<<<N / 128, 256, 0, stream>>>(aggr1, stats + 128);
    bn_finalize<<<1, 64, 0, stream>>>(stats + 128, gamma1, beta1, ssbuf + 128, invN);

    // ---- final linear (x2 = BN(aggr1) on load) ----
    out_kernel<<<N / 64, 256, 0, stream>>>(aggr1, W_lin, b_lin, (float*)d_out, ssbuf + 128);
}

// Round 5
// 339.667 us; speedup vs baseline: 1.3424x; 1.3424x over previous
//
#include <hip/hip_runtime.h>

typedef __bf16 bf16x8 __attribute__((ext_vector_type(8)));
typedef float f32x4 __attribute__((ext_vector_type(4)));

#define NEG_SLOPE 0.01f
#define BN_EPS 1e-5f

static __device__ __forceinline__ unsigned short f2bf(float f) {
    unsigned u = __builtin_bit_cast(unsigned, f);
    unsigned r = (u + 0x7fffu + ((u >> 16) & 1u)) >> 16;
    return (unsigned short)r;
}
static __device__ __forceinline__ float lrelu(float v) {
    return fmaxf(v, 0.f) + NEG_SLOPE * fminf(v, 0.f);
}
static __device__ __forceinline__ f32x4 bn4(f32x4 v, f32x4 sc, f32x4 sh) {
    f32x4 r = v * sc + sh;
    r.x = lrelu(r.x); r.y = lrelu(r.y); r.z = lrelu(r.z); r.w = lrelu(r.w);
    return r;
}

// ---- convert ef, W_edge0, W_edge1 to bf16; block 0 zeros stats + counters ----
__global__ __launch_bounds__(256) void cvt3(const float* __restrict__ a, int na4,
                                            const float* __restrict__ b, int nb4,
                                            const float* __restrict__ c, int nc4,
                                            unsigned short* __restrict__ oa,
                                            unsigned short* __restrict__ ob,
                                            unsigned short* __restrict__ oc,
                                            float* __restrict__ stats,
                                            int* __restrict__ counters) {
    int idx = blockIdx.x * 256 + threadIdx.x;
    if (blockIdx.x == 0) {
        stats[threadIdx.x] = 0.f;                 // stats[0..255]
        if (threadIdx.x < 2) counters[threadIdx.x] = 0;
    }
    const float* in; unsigned short* outp; int i;
    if (idx < na4)            { in = a; outp = oa; i = idx; }
    else if (idx < na4 + nb4) { in = b; outp = ob; i = idx - na4; }
    else                      { in = c; outp = oc; i = idx - na4 - nb4; }
    const f32x4 v = *reinterpret_cast<const f32x4*>(in + (size_t)i * 4);
    ushort4 u;
    u.x = f2bf(v.x); u.y = f2bf(v.y); u.z = f2bf(v.z); u.w = f2bf(v.w);
    *reinterpret_cast<ushort4*>(outp + (size_t)i * 4) = u;
}

// ---- root + node-bias matmuls; optional BN(x) on load ----
// y=0: aggr = BN(x)@Wr + br ; y=1: NB = BN(x)@be
__global__ __launch_bounds__(256) void node_mm2(const float* __restrict__ x,
                                                const float* __restrict__ Wr,
                                                const float* __restrict__ br,
                                                float* __restrict__ aggr,
                                                const float* __restrict__ be,
                                                float* __restrict__ NB,
                                                const float* __restrict__ ss) {
    const float* M; const float* bias; float* out;
    if (blockIdx.y == 0) { M = Wr; bias = br; out = aggr; }
    else                 { M = be; bias = nullptr; out = NB; }
    __shared__ float Ml[64][64];
    __shared__ float xl[64][64];
    const int tid = threadIdx.x;
    const int n0 = blockIdx.x * 64;
    for (int f = tid; f < 1024; f += 256) {
        int r = f >> 4, c = f & 15;
        *reinterpret_cast<float4*>(&Ml[r][c * 4]) =
            *reinterpret_cast<const float4*>(M + (size_t)r * 64 + c * 4);
        f32x4 xv = *reinterpret_cast<const f32x4*>(x + (size_t)(n0 + r) * 64 + c * 4);
        if (ss) {
            const f32x4 sc = *reinterpret_cast<const f32x4*>(ss + c * 4);
            const f32x4 sh = *reinterpret_cast<const f32x4*>(ss + 64 + c * 4);
            xv = bn4(xv, sc, sh);
        }
        *reinterpret_cast<f32x4*>(&xl[r][c * 4]) = xv;
    }
    __syncthreads();
    const int o = tid & 63, g = tid >> 6;
    float acc[16] = {};
    for (int i4 = 0; i4 < 16; ++i4) {
        float m0 = Ml[4 * i4 + 0][o], m1 = Ml[4 * i4 + 1][o];
        float m2 = Ml[4 * i4 + 2][o], m3 = Ml[4 * i4 + 3][o];
#pragma unroll
        for (int k = 0; k < 16; ++k) {
            const f32x4 xv = *reinterpret_cast<const f32x4*>(&xl[g + 4 * k][4 * i4]);
            acc[k] += xv.x * m0 + xv.y * m1 + xv.z * m2 + xv.w * m3;
        }
    }
    const float b = bias ? bias[o] : 0.f;
#pragma unroll
    for (int k = 0; k < 16; ++k)
        out[(size_t)(n0 + g + 4 * k) * 64 + o] = acc[k] + b;
}

// ---- fused NNConv message, o-split: block = 64 edges x o-slice [16y,16y+16) ----
// D_i[o,e] = sum_d W_i[o,d]*ef[e,d] (MFMA); acc[o,e] += x[src[e],i]*D_i over all i.
// Wave w = edge-tile w (16 edges). Adds NB[src][o-slice]; atomics to aggr[dst].
__global__ __launch_bounds__(256, 6) void msg_fused(
    const unsigned short* __restrict__ ef_b,   // [E][64] bf16
    const unsigned short* __restrict__ wb,     // [64][64][64] bf16 (i,o,d); + pad
    const float* __restrict__ x,               // [N][64] f32 (pre-BN if ss)
    const float* __restrict__ NB,              // [N][64] f32
    const int* __restrict__ src,
    const int* __restrict__ dst,
    float* __restrict__ aggr,                  // [N][64] f32
    const float* __restrict__ ss) {            // BN scale/shift for x, or null
    __shared__ float xT[64][64];               // xT[i][e] = BN(x)[src[e]][i]
    const int tid = threadIdx.x;
    const int e0 = blockIdx.x * 64;
    const int O0 = blockIdx.y * 16;

    // gather x rows of the 64 src nodes, transposed (f32, exact; BN on load)
#pragma unroll
    for (int it = 0; it < 4; ++it) {
        int f = it * 256 + tid;
        int e = f & 63, c = f >> 6;            // c in 0..15
        int s = src[e0 + e];
        f32x4 xv = *reinterpret_cast<const f32x4*>(x + (size_t)s * 64 + c * 4);
        if (ss) {
            const f32x4 sc = *reinterpret_cast<const f32x4*>(ss + c * 4);
            const f32x4 sh = *reinterpret_cast<const f32x4*>(ss + 64 + c * 4);
            xv = bn4(xv, sc, sh);
        }
        xT[4 * c + 0][e] = xv.x;
        xT[4 * c + 1][e] = xv.y;
        xT[4 * c + 2][e] = xv.z;
        xT[4 * c + 3][e] = xv.w;
    }

    const int w = tid >> 6, l = tid & 63, lg = l >> 4, ln = l & 15;
    const int ecol = 16 * w + ln;              // this lane's edge column

    // ef B-frag: wave's single 16-edge tile
    const unsigned short* pe = ef_b + (size_t)(e0 + ecol) * 64 + 8 * lg;
    const bf16x8 B0 = *reinterpret_cast<const bf16x8*>(pe);
    const bf16x8 B1 = *reinterpret_cast<const bf16x8*>(pe + 32);

    // W A-frag: row o = O0+ln of slice i; 2-deep register prefetch
    const unsigned short* pw = wb + (size_t)(O0 + ln) * 64 + 8 * lg;
    bf16x8 A0a = *reinterpret_cast<const bf16x8*>(pw);
    bf16x8 A1a = *reinterpret_cast<const bf16x8*>(pw + 32);
    bf16x8 A0b = *reinterpret_cast<const bf16x8*>(pw + 4096);
    bf16x8 A1b = *reinterpret_cast<const bf16x8*>(pw + 4096 + 32);

    __syncthreads();

    f32x4 acc = {};
#pragma unroll 2
    for (int i = 0; i < 64; ++i) {
        const unsigned short* pn = pw + (size_t)(i + 2) * 4096;
        const bf16x8 An0 = *reinterpret_cast<const bf16x8*>(pn);
        const bf16x8 An1 = *reinterpret_cast<const bf16x8*>(pn + 32);
        const float xs = xT[i][ecol];
        f32x4 c = {};
        c = __builtin_amdgcn_mfma_f32_16x16x32_bf16(A0a, B0, c, 0, 0, 0);
        c = __builtin_amdgcn_mfma_f32_16x16x32_bf16(A1a, B1, c, 0, 0, 0);
        acc += xs * c;
        A0a = A0b; A1a = A1b; A0b = An0; A1b = An1;
    }

    // epilogue: add NB[src][o-slice], scatter to aggr[dst][o-slice]
    const int e = e0 + ecol;
    const int s = src[e], d = dst[e];
    const f32x4 nbv = *reinterpret_cast<const f32x4*>(NB + (size_t)s * 64 + O0 + 4 * lg);
    const f32x4 add = acc + nbv;
#pragma unroll
    for (int rr = 0; rr < 4; ++rr)
        atomicAdd(aggr + (size_t)d * 64 + O0 + 4 * lg + rr, add[rr]);
}

// ---- BN statistics + last-block finalize (computes ss scale/shift) ----
__global__ __launch_bounds__(256) void bn_stats(const float* __restrict__ h,
                                                float* __restrict__ sums,
                                                const float* __restrict__ gamma,
                                                const float* __restrict__ beta,
                                                float* __restrict__ ss,
                                                float invN,
                                                int* __restrict__ counter,
                                                int nblk) {
    const int tid = threadIdx.x;
    const int o = tid & 63, g = tid >> 6;
    const int n0 = blockIdx.x * 128;
    float s = 0.f, s2 = 0.f;
    for (int k = 0; k < 32; ++k) {
        float v = h[(size_t)(n0 + g * 32 + k) * 64 + o];
        s += v; s2 += v * v;
    }
    __shared__ float red[2][4][64];
    __shared__ int lastFlag;
    red[0][g][o] = s; red[1][g][o] = s2;
    __syncthreads();
    if (g == 0) {
        s  = red[0][0][o] + red[0][1][o] + red[0][2][o] + red[0][3][o];
        s2 = red[1][0][o] + red[1][1][o] + red[1][2][o] + red[1][3][o];
        atomicAdd(&sums[o], s);
        atomicAdd(&sums[64 + o], s2);
    }
    __threadfence();
    __syncthreads();
    if (tid == 0) lastFlag = (atomicAdd(counter, 1) == nblk - 1);
    __syncthreads();
    if (lastFlag && tid < 64) {
        const float sv  = atomicAdd(&sums[tid], 0.f);        // coherent read
        const float sv2 = atomicAdd(&sums[64 + tid], 0.f);
        const float mean = sv * invN;
        const float var  = sv2 * invN - mean * mean;
        const float sc = gamma[tid] * rsqrtf(var + BN_EPS);
        ss[tid] = sc;
        ss[64 + tid] = beta[tid] - mean * sc;
    }
}

// ---- final: out[n,q] = sum_o BN(x)[n,o]*W_lin[q,o] + b_lin[q] ----
__global__ __launch_bounds__(256) void out_kernel(const float* __restrict__ x2,
                                                  const float* __restrict__ Wl,
                                                  const float* __restrict__ bl,
                                                  float* __restrict__ out,
                                                  const float* __restrict__ ss) {
    __shared__ float Wt[64][129];
    __shared__ float xl[64][64];
    const int tid = threadIdx.x;
    const int n0 = blockIdx.x * 64;
    for (int f = tid; f < 8192; f += 256) {
        int q = f >> 6, o = f & 63;
        Wt[o][q] = Wl[f];
    }
    for (int f = tid; f < 1024; f += 256) {
        int r = f >> 4, c = f & 15;
        f32x4 xv = *reinterpret_cast<const f32x4*>(x2 + (size_t)(n0 + r) * 64 + c * 4);
        const f32x4 sc = *reinterpret_cast<const f32x4*>(ss + c * 4);
        const f32x4 sh = *reinterpret_cast<const f32x4*>(ss + 64 + c * 4);
        xv = bn4(xv, sc, sh);
        *reinterpret_cast<f32x4*>(&xl[r][c * 4]) = xv;
    }
    __syncthreads();
    const int q = tid & 127, ng = tid >> 7;
    float acc[32] = {};
    for (int o4 = 0; o4 < 16; ++o4) {
        float w0 = Wt[4 * o4 + 0][q], w1 = Wt[4 * o4 + 1][q];
        float w2 = Wt[4 * o4 + 2][q], w3 = Wt[4 * o4 + 3][q];
#pragma unroll
        for (int k = 0; k < 32; ++k) {
            const f32x4 xv = *reinterpret_cast<const f32x4*>(&xl[ng + 2 * k][4 * o4]);
            acc[k] += xv.x * w0 + xv.y * w1 + xv.z * w2 + xv.w * w3;
        }
    }
    const float b = bl[q];
#pragma unroll
    for (int k = 0; k < 32; ++k)
        out[(size_t)(n0 + ng + 2 * k) * 128 + q] = acc[k] + b;
}

extern "C" void kernel_launch(void* const* d_in, const int* in_sizes, int n_in,
                              void* d_out, int out_size, void* d_ws, size_t ws_size,
                              hipStream_t stream) {
    const float* nf      = (const float*)d_in[0];
    const int*   ei      = (const int*)d_in[1];
    const float* ef      = (const float*)d_in[2];
    const float* W_edge0 = (const float*)d_in[4];
    const float* b_edge0 = (const float*)d_in[5];
    const float* W_root0 = (const float*)d_in[6];
    const float* b_root0 = (const float*)d_in[7];
    const float* gamma0  = (const float*)d_in[8];
    const float* beta0   = (const float*)d_in[9];
    const float* W_edge1 = (const float*)d_in[10];
    const float* b_edge1 = (const float*)d_in[11];
    const float* W_root1 = (const float*)d_in[12];
    const float* b_root1 = (const float*)d_in[13];
    const float* gamma1  = (const float*)d_in[14];
    const float* beta1   = (const float*)d_in[15];
    const float* W_lin   = (const float*)d_in[16];
    const float* b_lin   = (const float*)d_in[17];

    const int N = in_sizes[0] / 64;   // 8192
    const int E = in_sizes[1] / 2;    // 32768
    const int* src = ei;
    const int* dst = ei + E;

    unsigned short* ef_b = (unsigned short*)d_ws;          // E*64
    unsigned short* wb0  = ef_b + (size_t)E * 64;          // 64*64*64
    unsigned short* wb1  = wb0 + 262144;                   // 64*64*64
    unsigned short* pad  = wb1 + 262144;                   // 8192 (prefetch overrun)
    float* aggr0 = (float*)(pad + 8192);                   // N*64
    float* aggr1 = aggr0 + (size_t)N * 64;                 // N*64
    float* NBbuf = aggr1 + (size_t)N * 64;                 // N*64
    float* stats = NBbuf + (size_t)N * 64;                 // 256
    float* ssbuf = stats + 256;                            // 256
    int*   cnt   = (int*)(ssbuf + 256);                    // 2

    const float invN = 1.0f / (float)N;
    const int na4 = E * 64 / 4;          // 524288
    const int nw4 = 262144 / 4;          // 65536

    cvt3<<<(na4 + 2 * nw4) / 256, 256, 0, stream>>>(ef, na4, W_edge0, nw4, W_edge1, nw4,
                                                    ef_b, wb0, wb1, stats, cnt);

    // ---- layer 0 ----
    node_mm2<<<dim3(N / 64, 2), 256, 0, stream>>>(nf, W_root0, b_root0, aggr0,
                                                  b_edge0, NBbuf, nullptr);
    msg_fused<<<dim3(E / 64, 4), 256, 0, stream>>>(ef_b, wb0, nf, NBbuf, src, dst,
                                                   aggr0, nullptr);
    bn_stats<<<N / 128, 256, 0, stream>>>(aggr0, stats, gamma0, beta0, ssbuf,
                                          invN, cnt + 0, N / 128);

    // ---- layer 1 (x1 = BN(aggr0) applied on load everywhere) ----
    node_mm2<<<dim3(N / 64, 2), 256, 0, stream>>>(aggr0, W_root1, b_root1, aggr1,
                                                  b_edge1, NBbuf, ssbuf);
    msg_fused<<<dim3(E / 64, 4), 256, 0, stream>>>(ef_b, wb1, aggr0, NBbuf, src, dst,
                                                   aggr1, ssbuf);
    bn_stats<<<N / 128, 256, 0, stream>>>(aggr1, stats + 128, gamma1, beta1, ssbuf + 128,
                                          invN, cnt + 1, N / 128);

    // ---- final linear (x2 = BN(aggr1) on load) ----
    out_kernel<<<N / 64, 256, 0, stream>>>(aggr1, W_lin, b_lin, (float*)d_out, ssbuf + 128);
}